// Round 8
// baseline (114.804 us; speedup 1.0000x reference)
//
#include <hip/hip_runtime.h>

// Problem constants (fixed by setup_inputs): image (4,3,1024,1024) f32,
// pMtrx (4,2,3) f32, W=H=1024, align_corners=True.
//
// Forward-pass collapse: g0 = stop_gradient(grid) => grid - g0 == 0 exactly,
// so out = transpose(bilinear_sample(image, affine_grid(pMtrx,...)), (0,3,1,2)).
//
// R8: XCD-aware tile swizzle. R7 (~33us est) model: 123MB staged (2.44x band
// overlap) but raster tile order spreads adjacent tiles across the 8
// non-coherent per-XCD L2s -> overlap re-reads go to L3/HBM (~19.5us read).
// Remap blockIdx so XCD (bid&7, round-robin assumption) owns a contiguous
// half-image strip of one batch: band overlap of neighboring tiles becomes
// local-L2 hits (~5 concurrent tile-rows ~ 2.9MB < 4MB L2).
// Everything else identical to R7 (DMA staging, interior fast path).

#define B_  4
#define C_  3
#define HI  1024
#define WI  1024
#define HO  1024
#define WO  1024

#define TW  32
#define TH  32
#define BANDW 52                      // floats per band row (13 x float4)
#define BANDH 48
#define NSEG  13                      // BANDW/4
#define SEGS_CH (BANDH * NSEG)        // 624 float4-segments per channel
#define SEGS_TOT (C_ * SEGS_CH)       // 1872
#define LDS_CH (BANDH * BANDW)        // 2496 floats per channel
#define NITER ((SEGS_TOT + 63) / 64)  // 30 wave-wide DMA instructions

typedef __attribute__((address_space(3))) void* lds_vp;
typedef const __attribute__((address_space(1))) void* gbl_vp;

__device__ __forceinline__ float2 map_px(int w, int h,
                                         float t0, float t1, float t2,
                                         float t3, float t4, float t5) {
    const float xs = -1.0f + 2.0f * (float)w / (float)(WO - 1);
    const float ys = -1.0f + 2.0f * (float)h / (float)(HO - 1);
    const float x = t0 * xs + (t1 * ys + t2);
    const float y = t3 * xs + (t4 * ys + t5);
    const float ix = (x + 1.0f) * 0.5f * (float)(WI - 1);
    const float iy = (y + 1.0f) * 0.5f * (float)(HI - 1);
    return make_float2(ix, iy);
}

__global__ __launch_bounds__(256) void warp_bilinear_xcd_kernel(
    const float* __restrict__ image,   // (B, C, HI, WI)
    const float* __restrict__ theta,   // (B, 2, 3)
    float* __restrict__ out)           // (B, C, HO, WO)
{
    __shared__ float lds[NITER * 256];   // 7680 floats = 30720 B (tail pad)

    // ---- XCD-aware tile decode: XCD (bid&7) -> one half-image strip ----
    const int bid  = blockIdx.x;          // 0..4095
    const int xcd  = bid & 7;             // round-robin XCD assignment
    const int j    = bid >> 3;            // 0..511, raster within strip
    const int b    = xcd >> 1;            // 2 XCDs per batch image
    const int half = xcd & 1;             // top/bottom half (16 tile-rows)
    const int h0   = ((half << 4) + (j >> 5)) << 5;   // tile row * 32
    const int w0   = (j & 31) << 5;                   // tile col * 32

    const float* t = theta + b * 6;
    const float t0 = t[0], t1 = t[1], t2 = t[2];
    const float t3 = t[3], t4 = t[4], t5 = t[5];

    // ---- band bounding box from the 4 tile corners (block-uniform) ----
    const float2 c00 = map_px(w0,        h0,        t0,t1,t2,t3,t4,t5);
    const float2 c10 = map_px(w0+TW-1,   h0,        t0,t1,t2,t3,t4,t5);
    const float2 c01 = map_px(w0,        h0+TH-1,   t0,t1,t2,t3,t4,t5);
    const float2 c11 = map_px(w0+TW-1,   h0+TH-1,   t0,t1,t2,t3,t4,t5);

    const float ixmin = fminf(fminf(c00.x, c10.x), fminf(c01.x, c11.x));
    const float iymin = fminf(fminf(c00.y, c10.y), fminf(c01.y, c11.y));
    const float ixmax = fmaxf(fmaxf(c00.x, c10.x), fmaxf(c01.x, c11.x));
    const float iymax = fmaxf(fmaxf(c00.y, c10.y), fmaxf(c01.y, c11.y));

    int bx = (int)floorf(ixmin) - 1;
    bx = min(max(bx, 0), WI - BANDW);
    bx &= ~3;                            // 16B-align row base
    int by = (int)floorf(iymin) - 1;
    by = min(max(by, 0), HI - BANDH);

    const float* imgb = image + (size_t)b * (C_ * HI * WI);

    // ---- stage band via global_load_lds width=16 (no VGPR roundtrip) ----
    const int wv   = threadIdx.x >> 6;   // wave id 0..3
    const int lane = threadIdx.x & 63;
#pragma unroll
    for (int jj = wv; jj < NITER; jj += 4) {
        const int seg = jj * 64 + lane;
        if (seg < SEGS_TOT) {
            const int c  = seg / SEGS_CH;
            const int r2 = seg - c * SEGS_CH;
            const int r  = r2 / NSEG;
            const int s  = r2 - r * NSEG;
            const float* gp = imgb + c * (HI * WI) + (by + r) * WI + (bx + s * 4);
            __builtin_amdgcn_global_load_lds((gbl_vp)gp, (lds_vp)(lds + jj * 256),
                                             16, 0, 0);
        }
    }
    __syncthreads();

    // ---- compute: 4 rows per thread, consecutive-lane x (bank-free) ----
    const int wloc = threadIdx.x & 31;
    const int tyq  = threadIdx.x >> 5;   // 0..7
    const int w    = w0 + wloc;

    float* ob = out + (size_t)b * (C_ * HO * WO) + w;

    // block-uniform interior test: every tap strictly in-bounds
    const bool interior = (ixmin >= 1.0f) && (ixmax <= (float)(WI - 2)) &&
                          (iymin >= 1.0f) && (iymax <= (float)(HI - 2));

    if (interior) {
        // -------- fast path: no masks, no clamps, ds_read2-friendly ----
#pragma unroll
        for (int k = 0; k < 4; ++k) {
            const int h = h0 + tyq + 8 * k;
            const float2 ixy = map_px(w, h, t0, t1, t2, t3, t4, t5);
            const float ix = ixy.x, iy = ixy.y;

            const float x0f = floorf(ix);
            const float y0f = floorf(iy);
            const float wx1 = ix - x0f;
            const float wy1 = iy - y0f;
            const float wx0 = 1.0f - wx1;
            const float wy0 = 1.0f - wy1;

            const float w00 = wx0 * wy0, w10 = wx1 * wy0;
            const float w01 = wx0 * wy1, w11 = wx1 * wy1;

            const int ox = (int)x0f - bx;
            const int oy = (int)y0f - by;
            const float* base0 = lds + oy * BANDW + ox;

#pragma unroll
            for (int c = 0; c < C_; ++c) {
                const float* p = base0 + c * LDS_CH;
                const float v = p[0]         * w00 + p[1]         * w10
                              + p[BANDW]     * w01 + p[BANDW + 1] * w11;
                __builtin_nontemporal_store(v, ob + c * (HO * WO) + h * WO);
            }
        }
    } else {
        // -------- edge path: full validity-folded weights + clamps ------
#pragma unroll
        for (int k = 0; k < 4; ++k) {
            const int h = h0 + tyq + 8 * k;
            const float2 ixy = map_px(w, h, t0, t1, t2, t3, t4, t5);
            const float ix = ixy.x, iy = ixy.y;

            const float x0f = floorf(ix);
            const float y0f = floorf(iy);
            const float wx1 = ix - x0f;
            const float wy1 = iy - y0f;
            const int x0 = (int)x0f;
            const int y0 = (int)y0f;

            const float ax0 = (1.0f - wx1) * ((x0 >= 0 && x0 <= WI - 1) ? 1.0f : 0.0f);
            const float ax1 = wx1          * ((x0 >= -1 && x0 <= WI - 2) ? 1.0f : 0.0f);
            const float ay0 = (1.0f - wy1) * ((y0 >= 0 && y0 <= HI - 1) ? 1.0f : 0.0f);
            const float ay1 = wy1          * ((y0 >= -1 && y0 <= HI - 2) ? 1.0f : 0.0f);

            const float w00 = ax0 * ay0, w10 = ax1 * ay0;
            const float w01 = ax0 * ay1, w11 = ax1 * ay1;

            const int xl0 = min(max(min(max(x0,     0), WI - 1) - bx, 0), BANDW - 1);
            const int xl1 = min(max(min(max(x0 + 1, 0), WI - 1) - bx, 0), BANDW - 1);
            const int yl0 = min(max(min(max(y0,     0), HI - 1) - by, 0), BANDH - 1);
            const int yl1 = min(max(min(max(y0 + 1, 0), HI - 1) - by, 0), BANDH - 1);

            const int o00 = yl0 * BANDW + xl0;
            const int o10 = yl0 * BANDW + xl1;
            const int o01 = yl1 * BANDW + xl0;
            const int o11 = yl1 * BANDW + xl1;

#pragma unroll
            for (int c = 0; c < C_; ++c) {
                const float* p = lds + c * LDS_CH;
                const float v = p[o00] * w00 + p[o10] * w10
                              + p[o01] * w01 + p[o11] * w11;
                __builtin_nontemporal_store(v, ob + c * (HO * WO) + h * WO);
            }
        }
    }
}

extern "C" void kernel_launch(void* const* d_in, const int* in_sizes, int n_in,
                              void* d_out, int out_size, void* d_ws, size_t ws_size,
                              hipStream_t stream) {
    const float* image = (const float*)d_in[0];
    const float* theta = (const float*)d_in[1];
    float* out = (float*)d_out;

    const int grid = B_ * (HO / TH) * (WO / TW);   // 4*32*32 = 4096 blocks
    warp_bilinear_xcd_kernel<<<grid, 256, 0, stream>>>(image, theta, out);
}